// Round 20
// baseline (125.430 us; speedup 1.0000x reference)
//
#include <hip/hip_runtime.h>
#include <hip/hip_bf16.h>

#define D 128          // D_IN == D_OUT == 128
#define SCAN_CH 4096   // elements per scan block (256 threads x 16)
#define NP1 256        // coarse-bin pass blocks
#define BSH 9          // bucket = dst >> 9  (512 nodes per bucket)

typedef __bf16 bf16x8 __attribute__((ext_vector_type(8)));
typedef __bf16 bf16x4 __attribute__((ext_vector_type(4)));
typedef float  f32x4  __attribute__((ext_vector_type(4)));
typedef float  f32x2  __attribute__((ext_vector_type(2)));

__device__ __forceinline__ __bf16 f2bf(float f) { return (__bf16)f; }
__device__ __forceinline__ int pad8(int v) { return (v + 7) & ~7; }

// ---------------------------------------------------------------------------
// Prep: pack W into MFMA B-fragment order (bf16) + zero cnt.
// ---------------------------------------------------------------------------
__global__ __launch_bounds__(256) void prep_kernel(
    const float* __restrict__ W, __bf16* __restrict__ wb,
    int* __restrict__ cnt, int M)
{
    int t = blockIdx.x * 256 + threadIdx.x;
    for (int i = t; i < M; i += gridDim.x * 256) cnt[i] = 0;

    if (t < 2048) {
        int lane = t & 63;
        int frag = t >> 6;                           // 0..31 = kb*8+fn
        int kb = frag >> 3, fn = frag & 7;
        int n  = fn * 16 + (lane & 15);
        int k0 = kb * 32 + (lane >> 4) * 8;
        const float* src = &W[(size_t)n * D + k0];
        float4 v0 = *reinterpret_cast<const float4*>(src);
        float4 v1 = *reinterpret_cast<const float4*>(src + 4);
        bf16x8 o;
        o[0]=f2bf(v0.x); o[1]=f2bf(v0.y); o[2]=f2bf(v0.z); o[3]=f2bf(v0.w);
        o[4]=f2bf(v1.x); o[5]=f2bf(v1.y); o[6]=f2bf(v1.z); o[7]=f2bf(v1.w);
        *reinterpret_cast<bf16x8*>(&wb[((size_t)frag * 64 + lane) * 8]) = o;
    }
}

// ---------------------------------------------------------------------------
// Pass 1a (separate, measurable): coarse LDS bucket histogram + fire-and-
// forget global cnt[d]++.  No global atomic-returns.
// ---------------------------------------------------------------------------
__global__ __launch_bounds__(256) void p1a_kernel(
    const int* __restrict__ dst, int* __restrict__ cnt,
    int* __restrict__ cnts, int E, int chunk, int NBK)
{
    __shared__ int h[256];
    const int tid = threadIdx.x;
    h[tid] = 0;
    __syncthreads();
    int s = blockIdx.x * chunk;
    int e = s + chunk < E ? s + chunk : E;
    for (int i = s + tid; i < e; i += 256) {
        int d = dst[i];
        atomicAdd(&cnt[d], 1);          // fire-and-forget
        atomicAdd(&h[d >> BSH], 1);     // LDS
    }
    __syncthreads();
    if (tid < NBK) cnts[(size_t)tid * NP1 + blockIdx.x] = h[tid];
}

// ---------------------------------------------------------------------------
// GEMM (separate, measurable): y = x @ W^T via MFMA, LDS-staged x tile,
// PLAIN cached loads (no nontemporal anywhere), coalesced loads AND stores.
// LDS tile XOR-swizzled (byte ^= (row&7)<<4) per T2.
// ---------------------------------------------------------------------------
__global__ __launch_bounds__(256) void gemm_kernel(
    const float* __restrict__ x, const __bf16* __restrict__ wb,
    __bf16* __restrict__ y, int M)
{
    __shared__ char xs[128 * 256];     // 32 KB
    const int tid  = threadIdx.x;
    const int row0 = blockIdx.x * 128;
    const int lane = tid & 63;
    const int wv   = tid >> 6;
    const int l15  = lane & 15;
    const int l4   = lane >> 4;

    // ---- stage x tile: flat float4 mapping -> per-wave contiguous 1KB loads ----
    #pragma unroll
    for (int i = 0; i < 16; ++i) {
        int f  = tid + i * 256;         // float4 index 0..4095
        int r  = f >> 5;                // local row (32 float4 per row)
        int c8 = f & 31;
        int row = row0 + r;
        int rc  = row < M ? row : M - 1;
        f32x4 v = *reinterpret_cast<const f32x4*>(&x[(size_t)rc * D + c8 * 4]);
        bf16x4 o;
        o[0]=f2bf(v[0]); o[1]=f2bf(v[1]); o[2]=f2bf(v[2]); o[3]=f2bf(v[3]);
        int byte = r * 256 + ((c8 * 8) ^ ((r & 7) << 4));
        *reinterpret_cast<bf16x4*>(xs + byte) = o;
    }
    __syncthreads();

    // ---- MFMA: A-frags from swizzled LDS ----
    f32x4 acc[2][8];
    #pragma unroll
    for (int mi = 0; mi < 2; ++mi)
        #pragma unroll
        for (int fn = 0; fn < 8; ++fn)
            #pragma unroll
            for (int c = 0; c < 4; ++c) acc[mi][fn][c] = 0.f;

    #pragma unroll
    for (int kb = 0; kb < 4; ++kb) {
        bf16x8 b[8];
        #pragma unroll
        for (int fn = 0; fn < 8; ++fn)
            b[fn] = *reinterpret_cast<const bf16x8*>(
                        &wb[((size_t)(kb * 8 + fn) * 64 + lane) * 8]);
        #pragma unroll
        for (int mi = 0; mi < 2; ++mi) {
            int rl   = wv * 32 + mi * 16 + l15;
            int byte = rl * 256 + ((kb * 64 + l4 * 16) ^ ((rl & 7) << 4));
            bf16x8 a = *reinterpret_cast<const bf16x8*>(xs + byte);
            #pragma unroll
            for (int fn = 0; fn < 8; ++fn)
                acc[mi][fn] = __builtin_amdgcn_mfma_f32_16x16x32_bf16(
                                  a, b[fn], acc[mi][fn], 0, 0, 0);
        }
    }
    __syncthreads();   // xs reuse

    // ---- out fragments -> LDS (swizzled) ----
    #pragma unroll
    for (int mi = 0; mi < 2; ++mi)
        #pragma unroll
        for (int r = 0; r < 4; ++r) {
            int rl = wv * 32 + mi * 16 + l4 * 4 + r;
            #pragma unroll
            for (int fn = 0; fn < 8; ++fn) {
                int byte = rl * 256 + ((2 * (fn * 16 + l15)) ^ ((rl & 7) << 4));
                *reinterpret_cast<__bf16*>(xs + byte) = f2bf(acc[mi][fn][r]);
            }
        }
    __syncthreads();

    // ---- coalesced y stores ----
    #pragma unroll
    for (int i = 0; i < 8; ++i) {
        int g   = tid + i * 256;        // 16B chunk (16 per row)
        int r   = g >> 4;
        int c16 = g & 15;
        int row = row0 + r;
        if (row < M) {
            int byte = r * 256 + ((c16 * 16) ^ ((r & 7) << 4));
            bf16x8 v = *reinterpret_cast<const bf16x8*>(xs + byte);
            *reinterpret_cast<bf16x8*>(&y[(size_t)row * D + c16 * 8]) = v;
        }
    }
}

// ---------------------------------------------------------------------------
// Dual scan: blocks [0, NB_A) = pad8 scan of cnt -> base;
// blocks [NB_A, ...) = plain scan of cnts -> coffs.
// ---------------------------------------------------------------------------
__global__ __launch_bounds__(256) void scan2_part_kernel(
    const int* __restrict__ cnt, int N,
    const int* __restrict__ cnts, int NC,
    int* __restrict__ bsumA, int* __restrict__ bsumB, int NB_A)
{
    __shared__ int wred[4];
    const int tid  = threadIdx.x;
    const int lane = tid & 63;
    const int wid  = tid >> 6;
    const bool A   = (int)blockIdx.x < NB_A;
    const int blk  = A ? blockIdx.x : blockIdx.x - NB_A;
    int off = blk * SCAN_CH + tid * 16;
    int s = 0;
    #pragma unroll
    for (int i = 0; i < 16; ++i) {
        int idx = off + i;
        if (A) { if (idx < N)  s += pad8(cnt[idx]); }
        else   { if (idx < NC) s += cnts[idx]; }
    }
    #pragma unroll
    for (int d = 32; d >= 1; d >>= 1) s += __shfl_xor(s, d, 64);
    if (lane == 0) wred[wid] = s;
    __syncthreads();
    if (tid == 0) (A ? bsumA : bsumB)[blk] = wred[0] + wred[1] + wred[2] + wred[3];
}

__global__ __launch_bounds__(256) void scan2_write_kernel(
    const int* __restrict__ cnt, int N, int* __restrict__ base,
    const int* __restrict__ bsumA,
    const int* __restrict__ cnts, int NC, int* __restrict__ coffs,
    const int* __restrict__ bsumB, int NB_A)
{
    __shared__ int boff_s;
    __shared__ int wsum[4];
    const int tid  = threadIdx.x;
    const int lane = tid & 63;
    const int wid  = tid >> 6;
    const bool A   = (int)blockIdx.x < NB_A;
    const int blk  = A ? blockIdx.x : blockIdx.x - NB_A;

    if (wid == 0) {
        const int* bs = A ? bsumA : bsumB;
        int v = (lane < blk) ? bs[lane] : 0;   // NB <= 64
        #pragma unroll
        for (int d = 32; d >= 1; d >>= 1) v += __shfl_xor(v, d, 64);
        if (lane == 0) boff_s = v;
    }
    __syncthreads();

    int off = blk * SCAN_CH + tid * 16;
    int v[16];
    int s = 0;
    #pragma unroll
    for (int i = 0; i < 16; ++i) {
        int idx = off + i;
        if (A) v[i] = (idx < N)  ? pad8(cnt[idx]) : 0;
        else   v[i] = (idx < NC) ? cnts[idx] : 0;
        s += v[i];
    }
    int ssum = s;
    #pragma unroll
    for (int d = 1; d < 64; d <<= 1) {
        int t = __shfl_up(ssum, d, 64);
        if (lane >= d) ssum += t;
    }
    if (lane == 63) wsum[wid] = ssum;
    __syncthreads();
    int woff = 0;
    for (int w = 0; w < wid; ++w) woff += wsum[w];

    int run = boff_s + woff + ssum - s;
    #pragma unroll
    for (int i = 0; i < 16; ++i) {
        int idx = off + i;
        if (A) {
            if (idx < N) base[idx] = run;
            if (idx == N - 1) base[N] = run + v[i];   // padded total
        } else {
            if (idx < NC) coffs[idx] = run;
        }
        run += v[i];
    }
}

// ---------------------------------------------------------------------------
// Pass 1b: scatter edges into bucket-contiguous coarse arrays via LDS cursors.
// ---------------------------------------------------------------------------
__global__ __launch_bounds__(256) void p1b_kernel(
    const int* __restrict__ src, const int* __restrict__ dst,
    const float* __restrict__ ew, const int* __restrict__ coffs,
    int* __restrict__ cDst, int2* __restrict__ cSW, int E, int chunk, int NBK)
{
    __shared__ int h[256];
    const int tid = threadIdx.x;
    const int k   = blockIdx.x;
    if (tid < NBK) h[tid] = coffs[(size_t)tid * NP1 + k];
    __syncthreads();
    int s = k * chunk;
    int e = s + chunk < E ? s + chunk : E;
    for (int i = s + tid; i < e; i += 256) {
        int d  = dst[i];
        int p  = atomicAdd(&h[d >> BSH], 1);     // LDS atomic-return
        cDst[p] = d;
        cSW[p]  = make_int2(src[i] * (D / 2), __float_as_int(ew[i]));
    }
}

// ---------------------------------------------------------------------------
// Pass 2: one block per bucket; cursors in LDS; place edges + write pad slots.
// ---------------------------------------------------------------------------
__global__ __launch_bounds__(256) void p2_kernel(
    const int* __restrict__ cDst, const int2* __restrict__ cSW,
    const int* __restrict__ coffs, const int* __restrict__ base,
    int2* __restrict__ bins, int M, int E, int NBK)
{
    __shared__ int cur[512];
    const int tid = threadIdx.x;
    const int b   = blockIdx.x;
    const int n0  = b << BSH;

    for (int ld = tid; ld < 512; ld += 256) {
        int n = n0 + ld;
        cur[ld] = (n < M) ? base[n] : 0;
    }
    __syncthreads();

    int e0 = coffs[(size_t)b * NP1];
    int e1 = (b + 1 < NBK) ? coffs[(size_t)(b + 1) * NP1] : E;
    for (int i = e0 + tid; i < e1; i += 256) {
        int ld = cDst[i] & 511;
        int p  = atomicAdd(&cur[ld], 1);         // LDS atomic-return
        bins[p] = cSW[i];
    }
    __syncthreads();

    const int2 z = make_int2(0, 0);
    for (int ld = tid; ld < 512; ld += 256) {
        int n = n0 + ld;
        if (n < M) {
            int end = base[n + 1];
            for (int p = cur[ld]; p < end; ++p) bins[p] = z;
        }
    }
}

// ---------------------------------------------------------------------------
// Gather-sum from bf16 y: one wave per node, 8 edges in flight.
// ---------------------------------------------------------------------------
__global__ __launch_bounds__(256) void gather_kernel(
    const __bf16* __restrict__ y, const int* __restrict__ base,
    const int2* __restrict__ bins, const float* __restrict__ bias,
    float* __restrict__ out, int N)
{
    int gw   = (blockIdx.x * 256 + threadIdx.x) >> 6;
    int lane = threadIdx.x & 63;
    if (gw >= N) return;

    const unsigned* yb = reinterpret_cast<const unsigned*>(y);  // 2 bf16 / uint
    const int b0 = __builtin_amdgcn_readfirstlane(base[gw]);
    const int b1 = __builtin_amdgcn_readfirstlane(base[gw + 1]);
    float accx = 0.f, accy = 0.f;

    for (int i = b0; i < b1; i += 8) {
        int2 e[8];
        #pragma unroll
        for (int t = 0; t < 8; ++t) e[t] = bins[i + t];
        unsigned p[8];
        #pragma unroll
        for (int t = 0; t < 8; ++t)
            p[t] = yb[(unsigned)e[t].x + lane];
        #pragma unroll
        for (int t = 0; t < 8; ++t) {
            float w = __int_as_float(e[t].y);
            accx += __uint_as_float(p[t] << 16) * w;
            accy += __uint_as_float(p[t] & 0xFFFF0000u) * w;
        }
    }

    float2 bv = *reinterpret_cast<const float2*>(&bias[lane * 2]);
    f32x2 o;
    o[0] = accx + bv.x;
    o[1] = accy + bv.y;
    __builtin_nontemporal_store(o, reinterpret_cast<f32x2*>(&out[(size_t)gw * D + lane * 2]));
}

extern "C" void kernel_launch(void* const* d_in, const int* in_sizes, int n_in,
                              void* d_out, int out_size, void* d_ws, size_t ws_size,
                              hipStream_t stream) {
    const float* x   = (const float*)d_in[0];
    const float* ew  = (const float*)d_in[1];
    const int*   src = (const int*)d_in[2];
    const int*   dst = (const int*)d_in[3];
    const float* W   = (const float*)d_in[4];
    const float* b   = (const float*)d_in[5];
    float*       out = (float*)d_out;

    const int E     = in_sizes[2];                  // 640000
    const int M     = out_size / D;                 // 100000 nodes
    const int NBK   = (M + 511) >> BSH;             // 196 buckets
    const int NC    = NBK * NP1;                    // 50176
    const int chunk = (E + NP1 - 1) / NP1;          // 2500
    const int NB_A  = (M + SCAN_CH - 1) / SCAN_CH;  // 25  (<=64)
    const int NB_B  = (NC + SCAN_CH - 1) / SCAN_CH; // 13  (<=64)
    const size_t BIN_CAP = (size_t)E + 7 * (size_t)M + 8;

    // ws layout
    char* p = (char*)d_ws;
    __bf16* y     = (__bf16*)p;            p += (size_t)M * D * 2;
    __bf16* wb    = (__bf16*)p;            p += (size_t)32 * 64 * 8 * 2;
    int2*   bins  = (int2*)p;              p += BIN_CAP * 8;
    int*    base  = (int*)p;               p += (size_t)(M + 1) * 4;
    int*    cnt   = (int*)p;               p += (size_t)M * 4;
    int*    cnts  = (int*)p;               p += (size_t)NC * 4;
    int*    coffs = (int*)p;               p += (size_t)NC * 4;
    int*    cDst  = (int*)p;               p += (size_t)E * 4;
    int2*   cSW   = (int2*)p;              p += (size_t)E * 8;
    int*    bsumA = (int*)p;               p += 64 * 4;
    int*    bsumB = (int*)p;

    // 1) pack W + zero cnt
    prep_kernel<<<64, 256, 0, stream>>>(W, wb, cnt, M);

    // 2) coarse hist (separate, measurable)
    p1a_kernel<<<NP1, 256, 0, stream>>>(dst, cnt, cnts, E, chunk, NBK);

    // 3) MFMA GEMM (separate, measurable; no nontemporal)
    gemm_kernel<<<(M + 127) / 128, 256, 0, stream>>>(x, wb, y, M);

    // 4-5) dual scan: cnt->base (pad8) || cnts->coffs
    scan2_part_kernel<<<NB_A + NB_B, 256, 0, stream>>>(
        cnt, M, cnts, NC, bsumA, bsumB, NB_A);
    scan2_write_kernel<<<NB_A + NB_B, 256, 0, stream>>>(
        cnt, M, base, bsumA, cnts, NC, coffs, bsumB, NB_A);

    // 6) coarse scatter (LDS cursors)
    p1b_kernel<<<NP1, 256, 0, stream>>>(src, dst, ew, coffs, cDst, cSW, E, chunk, NBK);

    // 7) per-bucket final placement + pad writes (LDS cursors)
    p2_kernel<<<NBK, 256, 0, stream>>>(cDst, cSW, coffs, base, bins, M, E, NBK);

    // 8) out[n] = sum_{e in node n} y[src_e] * w_e + bias
    gather_kernel<<<(M * 64 + 255) / 256, 256, 0, stream>>>(y, base, bins, b, out, M);
}